// Round 3
// baseline (174.625 us; speedup 1.0000x reference)
//
#include <hip/hip_runtime.h>

#define B_TOT 1024   // BATCH * nbr = 64 * 16
#define L_DIM 64
#define K_DIM 32
#define IN1   64
#define OUT_K 32
#define EPS_BN 1e-5f

__device__ __forceinline__ float reduce64(float v) {
    #pragma unroll
    for (int w = 1; w < 64; w <<= 1) v += __shfl_xor(v, w);
    return v;
}

// ---------------------------------------------------------------------------
// Kernel 1: Hmk[b,c,l] = mean_k H[b,c,l,k], Hml[b,c,k] = mean_l H[b,c,l,k]
// where H[b, ri*4+u, l, k] = Hhat_{ri}[b, l, k, u]
// LDS row stride padded to 132 words: column sums (stride 4 within row,
// stride 132 across rows) then hit (4l+4k+u)%32 -> 2-way max (free).
// ---------------------------------------------------------------------------
__global__ __launch_bounds__(256) void hmeans_kernel(const float* __restrict__ Hr,
                                                     const float* __restrict__ Hi,
                                                     float* __restrict__ Hmk,
                                                     float* __restrict__ Hml) {
    __shared__ float tile[64 * 132];
    int b = blockIdx.x;
    int tid = threadIdx.x;
    for (int ri = 0; ri < 2; ++ri) {
        const float* src = (ri == 0 ? Hr : Hi) + (size_t)b * 8192;
        const float4* src4 = (const float4*)src;
        for (int j = tid; j < 2048; j += 256) {
            float4 v = src4[j];
            int l = j >> 5, w0 = (j & 31) * 4;
            float* d = &tile[l * 132 + w0];
            d[0] = v.x; d[1] = v.y; d[2] = v.z; d[3] = v.w;
        }
        __syncthreads();
        {
            int l = tid >> 2, u = tid & 3;
            float s = 0.f;
            #pragma unroll
            for (int kk = 0; kk < 32; ++kk) s += tile[l * 132 + kk * 4 + u];
            Hmk[(size_t)b * 512 + (ri * 4 + u) * 64 + l] = s * (1.0f / 32.0f);
        }
        if (tid < 128) {
            int kk = tid >> 2, u = tid & 3;
            float s = 0.f;
            #pragma unroll
            for (int l = 0; l < 64; ++l) s += tile[l * 132 + kk * 4 + u];
            Hml[(size_t)b * 256 + (ri * 4 + u) * 32 + kk] = s * (1.0f / 64.0f);
        }
        __syncthreads();
    }
}

// ---------------------------------------------------------------------------
// Hidden layer, register-resident, zero LDS.
// Block = one b, 4 waves; wave w computes outputs o in [w*16, w*16+16).
// Lane l holds column l of A_AP (all 64 i) and column (l&31) of A_UE
// (duplicated across half-waves). Q/P loads are wave-uniform -> s_load.
//   new_AP[o,l] = relu(2*Q1a[o,:]@aAP + 2*mean_l(Q2u... ) ...)
// bias terms: mean over spatial of (Q2 @ A) computed per-o via butterfly.
// BN of PREVIOUS layer folded into the register load (coefIn).
// Stats (post-ReLU sum/sumsq per channel) -> statsS/statsQ[ch*1024+b].
// ---------------------------------------------------------------------------
__global__ __launch_bounds__(256) void layer_hidden_kernel(
    const float* __restrict__ Aap_in, const float* __restrict__ Aue_in,
    float* __restrict__ Aap_out, float* __restrict__ Aue_out,
    const float* __restrict__ Hmk, const float* __restrict__ Hml,
    const float* __restrict__ Q,   // Q1a | Q2a | Q1u | Q2u, each 64x64
    const float* __restrict__ P,   // P1a | P1u, each 64x8
    const float* __restrict__ coefIn, // scAP[64] shAP[64] scUE[64] shUE[64]
    float* __restrict__ statsS, float* __restrict__ statsQ,
    int first) {
    int b = blockIdx.x, tid = threadIdx.x;
    int l = tid & 63, k = l & 31;

    float hmk[8], hml[8];
    #pragma unroll
    for (int c = 0; c < 8; ++c) hmk[c] = Hmk[(size_t)b * 512 + c * 64 + l];
    #pragma unroll
    for (int c = 0; c < 8; ++c) hml[c] = Hml[(size_t)b * 256 + c * 32 + k];

    float aAP[64], aUE[64];
    if (!first) {
        #pragma unroll
        for (int i = 0; i < 64; ++i)
            aAP[i] = Aap_in[(size_t)b * 4096 + i * 64 + l] * coefIn[i] + coefIn[64 + i];
        #pragma unroll
        for (int i = 0; i < 64; ++i)
            aUE[i] = Aue_in[(size_t)b * 2048 + i * 32 + k] * coefIn[128 + i] + coefIn[192 + i];
    }

    const float* Q1a = Q;
    const float* Q2a = Q + 4096;
    const float* Q1u = Q + 2 * 4096;
    const float* Q2u = Q + 3 * 4096;

    for (int m = 0; m < 16; ++m) {
        int o = __builtin_amdgcn_readfirstlane((tid >> 6) * 16 + m);
        float pa = 0.f, pu = 0.f;
        #pragma unroll
        for (int c = 0; c < 8; ++c) {
            pa += P[o * 8 + c] * hmk[c];
            pu += P[512 + o * 8 + c] * hml[c];
        }
        float vAP, vUE;
        if (!first) {
            float t1 = 0.f, t2 = 0.f, t3 = 0.f, t4 = 0.f;
            #pragma unroll
            for (int i = 0; i < 64; ++i) {
                t1 += Q1a[o * 64 + i] * aAP[i];
                t2 += Q2a[o * 64 + i] * aUE[i];
                t3 += Q1u[o * 64 + i] * aUE[i];
                t4 += Q2u[o * 64 + i] * aAP[i];
            }
            // mean_k(Q2a@A_UE)[o]: aUE duplicated -> sum64/64 == sum32/32
            float t2m = reduce64(t2) * (1.0f / 64.0f);
            // mean_l(Q2u@A_AP)[o]: 64 distinct lanes -> sum64/64
            float t4m = reduce64(t4) * (1.0f / 64.0f);
            vAP = fmaxf(2.f * t1 + 2.f * t2m + 0.1f * pa, 0.f);
            vUE = fmaxf(2.f * t3 + 2.f * t4m + 0.1f * pu, 0.f);
        } else {
            vAP = fmaxf(0.1f * pa, 0.f);
            vUE = fmaxf(0.1f * pu, 0.f);
        }
        Aap_out[(size_t)b * 4096 + o * 64 + l] = vAP;
        if (l < 32) Aue_out[(size_t)b * 2048 + o * 32 + k] = vUE;

        float sS = reduce64(vAP);
        float sQ = reduce64(vAP * vAP);
        float uS = reduce64(vUE) * 0.5f;        // duplicated halves
        float uQ = reduce64(vUE * vUE) * 0.5f;
        if (l == 0) {
            statsS[o * 1024 + b] = sS;
            statsQ[o * 1024 + b] = sQ;
            statsS[(64 + o) * 1024 + b] = uS;
            statsQ[(64 + o) * 1024 + b] = uQ;
        }
    }
}

// ---------------------------------------------------------------------------
// BN finalize: one block per channel (128 blocks). Reduces 1024 per-block
// partials, computes scale/shift: coef = scAP[64] shAP[64] scUE[64] shUE[64]
// ---------------------------------------------------------------------------
__global__ __launch_bounds__(256) void bn_finalize_kernel(
    const float* __restrict__ statsS, const float* __restrict__ statsQ,
    const float* __restrict__ gamma, const float* __restrict__ beta,
    float* __restrict__ coef) {
    __shared__ float redS[4], redQ[4];
    int ch = blockIdx.x;   // 0..127
    int tid = threadIdx.x;
    float s = 0.f, q = 0.f;
    for (int j = tid; j < 1024; j += 256) {
        s += statsS[ch * 1024 + j];
        q += statsQ[ch * 1024 + j];
    }
    s = reduce64(s);
    q = reduce64(q);
    int wave = tid >> 6, lane = tid & 63;
    if (lane == 0) { redS[wave] = s; redQ[wave] = q; }
    __syncthreads();
    if (tid == 0) {
        s = redS[0] + redS[1] + redS[2] + redS[3];
        q = redQ[0] + redQ[1] + redQ[2] + redQ[3];
        bool ap = ch < 64;
        int o = ap ? ch : ch - 64;
        float cnt = ap ? (float)(B_TOT * L_DIM) : (float)(B_TOT * K_DIM);
        float m = s / cnt;
        float var = q / cnt - m * m;
        float sc = gamma[o] / sqrtf(var + EPS_BN);
        if (ap) { coef[o] = sc;       coef[64 + o] = beta[o] - m * sc; }
        else    { coef[128 + o] = sc; coef[192 + o] = beta[o] - m * sc; }
    }
}

// ---------------------------------------------------------------------------
// Output layer (AP path only, out=32 channels, no act/BN), register-resident.
// 4 waves, 8 outputs each. Applies coefIn (BN of last hidden layer) on load.
// ---------------------------------------------------------------------------
__global__ __launch_bounds__(256) void layer_out_kernel(
    const float* __restrict__ Aap_in, const float* __restrict__ Aue_in,
    const float* __restrict__ Hmk,
    const float* __restrict__ Qo,  // Q1a | Q2a | Q1u | Q2u, each 32x64
    const float* __restrict__ Po,  // P1a | P1u, each 32x8
    const float* __restrict__ coefIn,
    float* __restrict__ V) {
    int b = blockIdx.x, tid = threadIdx.x;
    int l = tid & 63, k = l & 31;

    float hmk[8];
    #pragma unroll
    for (int c = 0; c < 8; ++c) hmk[c] = Hmk[(size_t)b * 512 + c * 64 + l];

    float aAP[64], aUE[64];
    #pragma unroll
    for (int i = 0; i < 64; ++i)
        aAP[i] = Aap_in[(size_t)b * 4096 + i * 64 + l] * coefIn[i] + coefIn[64 + i];
    #pragma unroll
    for (int i = 0; i < 64; ++i)
        aUE[i] = Aue_in[(size_t)b * 2048 + i * 32 + k] * coefIn[128 + i] + coefIn[192 + i];

    const float* Q1o = Qo;
    const float* Q2o = Qo + OUT_K * 64;

    for (int m = 0; m < 8; ++m) {
        int o = __builtin_amdgcn_readfirstlane((tid >> 6) * 8 + m);
        float pa = 0.f;
        #pragma unroll
        for (int c = 0; c < 8; ++c) pa += Po[o * 8 + c] * hmk[c];
        float t1 = 0.f, t2 = 0.f;
        #pragma unroll
        for (int i = 0; i < 64; ++i) {
            t1 += Q1o[o * 64 + i] * aAP[i];
            t2 += Q2o[o * 64 + i] * aUE[i];
        }
        float t2m = reduce64(t2) * (1.0f / 64.0f);
        V[(size_t)b * 2048 + o * 64 + l] = 2.f * t1 + 2.f * t2m + 0.1f * pa;
    }
}

// ---------------------------------------------------------------------------
// Final: Phat1[bb,r,l,k] = V[b,k,l]; norm over l; Fhat = Vhat * Phat1/norm*sqrt(L)
// ---------------------------------------------------------------------------
__global__ __launch_bounds__(256) void finalize_kernel(const float* __restrict__ V,
                                                       const float* __restrict__ Vhat,
                                                       float* __restrict__ out) {
    __shared__ float sV[32 * 65];
    __shared__ float inv[32];
    int b = blockIdx.x, tid = threadIdx.x;
    const float4* v4 = (const float4*)(V + (size_t)b * 2048);
    for (int j = tid; j < 512; j += 256) {
        float4 x = v4[j];
        int kk = j >> 4, l0 = (j & 15) * 4;
        float* d = &sV[kk * 65 + l0];
        d[0] = x.x; d[1] = x.y; d[2] = x.z; d[3] = x.w;
    }
    __syncthreads();
    if (tid < 32) {
        float s = 0.f;
        #pragma unroll
        for (int l = 0; l < 64; ++l) { float x = sV[tid * 65 + l]; s += x * x; }
        inv[tid] = 8.0f / sqrtf(s); // sqrt(L)=8
    }
    __syncthreads();
    const float4* vh4 = (const float4*)(Vhat + (size_t)b * 8192);
    float4* o4 = (float4*)out + (size_t)b * 2048;
    for (int j = tid; j < 2048; j += 256) {
        int l = j >> 5, kk = j & 31;
        float p = sV[kk * 65 + l] * inv[kk];
        float4 x = vh4[j];
        x.x *= p; x.y *= p; x.z *= p; x.w *= p;
        o4[j] = x;
    }
}

// ---------------------------------------------------------------------------
extern "C" void kernel_launch(void* const* d_in, const int* in_sizes, int n_in,
                              void* d_out, int out_size, void* d_ws, size_t ws_size,
                              hipStream_t stream) {
    const float* Hr        = (const float*)d_in[0];
    const float* Hi        = (const float*)d_in[1];
    const float* Vhat      = (const float*)d_in[2];
    const float* Qs_hidden = (const float*)d_in[3];
    const float* Ps_hidden = (const float*)d_in[4];
    const float* Qs_out    = (const float*)d_in[5];
    const float* Ps_out    = (const float*)d_in[6];
    const float* bn_gamma  = (const float*)d_in[7];
    const float* bn_beta   = (const float*)d_in[8];
    float* out = (float*)d_out;

    float* ws     = (float*)d_ws;
    float* Hmk    = ws;                    // 1024*512
    float* Hml    = Hmk + 524288;          // 1024*256
    float* AapA   = Hml + 262144;          // 1024*4096
    float* AueA   = AapA + 4194304;        // 1024*2048
    float* AapB   = AueA + 2097152;        // 1024*4096
    float* AueB   = AapB + 4194304;        // 1024*2048
    float* statsS = AueB + 2097152;        // 128*1024
    float* statsQ = statsS + 131072;       // 128*1024
    float* coefA  = statsQ + 131072;       // 256
    float* coefB  = coefA + 256;           // 256
    float* V      = AapA;                  // alias: AapA dead after layer 1 reads it

    hipLaunchKernelGGL(hmeans_kernel, dim3(B_TOT), dim3(256), 0, stream, Hr, Hi, Hmk, Hml);

    // hidden layer 0 (inputs are zero -> only P-path)
    hipLaunchKernelGGL(layer_hidden_kernel, dim3(B_TOT), dim3(256), 0, stream,
                       (const float*)nullptr, (const float*)nullptr, AapA, AueA,
                       Hmk, Hml, Qs_hidden, Ps_hidden,
                       (const float*)nullptr, statsS, statsQ, 1);
    hipLaunchKernelGGL(bn_finalize_kernel, dim3(128), dim3(256), 0, stream,
                       statsS, statsQ, bn_gamma, bn_beta, coefA);

    // hidden layer 1 (applies coefA on load)
    hipLaunchKernelGGL(layer_hidden_kernel, dim3(B_TOT), dim3(256), 0, stream,
                       AapA, AueA, AapB, AueB,
                       Hmk, Hml, Qs_hidden + 4 * 4096, Ps_hidden + 2 * 512,
                       coefA, statsS, statsQ, 0);
    hipLaunchKernelGGL(bn_finalize_kernel, dim3(128), dim3(256), 0, stream,
                       statsS, statsQ, bn_gamma + 64, bn_beta + 64, coefB);

    // output layer (applies coefB on load) + normalization/scale
    hipLaunchKernelGGL(layer_out_kernel, dim3(B_TOT), dim3(256), 0, stream,
                       AapB, AueB, Hmk, Qs_out, Ps_out, coefB, V);
    hipLaunchKernelGGL(finalize_kernel, dim3(B_TOT), dim3(256), 0, stream, V, Vhat, out);
}

// Round 4
// 128.570 us; speedup vs baseline: 1.3582x; 1.3582x over previous
//
#include <hip/hip_runtime.h>

#define B_TOT 1024   // BATCH * nbr = 64 * 16
#define L_DIM 64
#define K_DIM 32
#define OUT_K 32
#define EPS_BN 1e-5f

__device__ __forceinline__ float reduce64(float v) {
    #pragma unroll
    for (int w = 1; w < 64; w <<= 1) v += __shfl_xor(v, w);
    return v;
}

// ---------------------------------------------------------------------------
// Kernel 1: Hmk[b,c,l] = mean_k H[b,c,l,k], Hml[b,c,k] = mean_l H[b,c,l,k]
// where H[b, ri*4+u, l, k] = Hhat_{ri}[b, l, k, u]
// LDS row stride padded to 132 words to break column-sum bank conflicts.
// ---------------------------------------------------------------------------
__global__ __launch_bounds__(256) void hmeans_kernel(const float* __restrict__ Hr,
                                                     const float* __restrict__ Hi,
                                                     float* __restrict__ Hmk,
                                                     float* __restrict__ Hml) {
    __shared__ float tile[64 * 132];
    int b = blockIdx.x;
    int tid = threadIdx.x;
    for (int ri = 0; ri < 2; ++ri) {
        const float* src = (ri == 0 ? Hr : Hi) + (size_t)b * 8192;
        const float4* src4 = (const float4*)src;
        for (int j = tid; j < 2048; j += 256) {
            float4 v = src4[j];
            int l = j >> 5, w0 = (j & 31) * 4;
            float* d = &tile[l * 132 + w0];
            d[0] = v.x; d[1] = v.y; d[2] = v.z; d[3] = v.w;
        }
        __syncthreads();
        {
            int l = tid >> 2, u = tid & 3;
            float s = 0.f;
            #pragma unroll
            for (int kk = 0; kk < 32; ++kk) s += tile[l * 132 + kk * 4 + u];
            Hmk[(size_t)b * 512 + (ri * 4 + u) * 64 + l] = s * (1.0f / 32.0f);
        }
        if (tid < 128) {
            int kk = tid >> 2, u = tid & 3;
            float s = 0.f;
            #pragma unroll
            for (int l = 0; l < 64; ++l) s += tile[l * 132 + kk * 4 + u];
            Hml[(size_t)b * 256 + (ri * 4 + u) * 32 + kk] = s * (1.0f / 64.0f);
        }
        __syncthreads();
    }
}

// ---------------------------------------------------------------------------
// Hidden layer, wave-specialized, zero LDS, no spills.
// Block = one b, 4 waves. Waves 0,1: AP path (o in [0,32)/[32,64), lane = l,
// holds aAP[64]). Waves 2,3: UE path (lane = k duplicated, holds aUE[64]).
// Cross-term uses linearity: mean_sp(Q2@A_bn) = Q2 @ (sc*meanRaw+sh), where
// meanRaw comes from muIn[b*128+ch] (raw per-b channel sums from producer).
// BN of previous layer folded into register load (coefIn).
// Outputs: activations (pre-BN), statsS/statsQ[ch*1024+b] (ch-major for
// bn_finalize), muOut[b*128+ch] (b-major raw sums for next layer's bias).
// ---------------------------------------------------------------------------
__global__ __launch_bounds__(256) void layer_hidden_kernel(
    const float* __restrict__ Aap_in, const float* __restrict__ Aue_in,
    float* __restrict__ Aap_out, float* __restrict__ Aue_out,
    const float* __restrict__ Hmk, const float* __restrict__ Hml,
    const float* __restrict__ Q,   // Q1a | Q2a | Q1u | Q2u, each 64x64
    const float* __restrict__ P,   // P1a | P1u, each 64x8
    const float* __restrict__ coefIn, // scAP[64] shAP[64] scUE[64] shUE[64]
    const float* __restrict__ muIn,   // [b][128] raw sums (AP: /64, UE: /32)
    float* __restrict__ statsS, float* __restrict__ statsQ,
    float* __restrict__ muOut,
    int first) {
    int b = blockIdx.x, tid = threadIdx.x;
    int wid = tid >> 6, lane = tid & 63;
    int o0 = (wid & 1) * 32;

    if (wid < 2) {
        // ------------------- AP path: lane = l -------------------
        float hmk[8];
        #pragma unroll
        for (int c = 0; c < 8; ++c) hmk[c] = Hmk[(size_t)b * 512 + c * 64 + lane];
        float a[64];
        float mu_ue = 0.f;
        if (!first) {
            #pragma unroll
            for (int i = 0; i < 64; ++i)
                a[i] = Aap_in[(size_t)b * 4096 + i * 64 + lane] * coefIn[i] + coefIn[64 + i];
            // BN'd per-b mean over k of A_UE, element i = lane
            mu_ue = muIn[b * 128 + 64 + lane] * (1.0f / 32.0f) * coefIn[128 + lane]
                  + coefIn[192 + lane];
        }
        for (int m = 0; m < 32; ++m) {
            int o = __builtin_amdgcn_readfirstlane(o0 + m);
            const float4* Prow = (const float4*)(P + o * 8);
            float4 p0 = Prow[0], p1 = Prow[1];
            float pa = p0.x * hmk[0] + p0.y * hmk[1] + p0.z * hmk[2] + p0.w * hmk[3]
                     + p1.x * hmk[4] + p1.y * hmk[5] + p1.z * hmk[6] + p1.w * hmk[7];
            float acc = 0.1f * pa;
            if (!first) {
                const float4* Qrow = (const float4*)(Q + o * 64);   // Q1a row
                float t1 = 0.f;
                #pragma unroll
                for (int j = 0; j < 16; ++j) {
                    float4 q = Qrow[j];
                    t1 += q.x * a[4 * j] + q.y * a[4 * j + 1]
                        + q.z * a[4 * j + 2] + q.w * a[4 * j + 3];
                }
                float t2 = reduce64(Q[4096 + o * 64 + lane] * mu_ue); // Q2a @ mu
                acc += 2.f * t1 + 2.f * t2;
            }
            float v = fmaxf(acc, 0.f);
            Aap_out[(size_t)b * 4096 + o * 64 + lane] = v;
            float sS = reduce64(v);
            float sQ = reduce64(v * v);
            if (lane == 0) {
                statsS[o * 1024 + b] = sS;
                statsQ[o * 1024 + b] = sQ;
                muOut[b * 128 + o] = sS;
            }
        }
    } else {
        // ------------------- UE path: lane = k (duplicated halves) ----------
        int k = lane & 31;
        float hml[8];
        #pragma unroll
        for (int c = 0; c < 8; ++c) hml[c] = Hml[(size_t)b * 256 + c * 32 + k];
        float a[64];
        float mu_ap = 0.f;
        if (!first) {
            #pragma unroll
            for (int i = 0; i < 64; ++i)
                a[i] = Aue_in[(size_t)b * 2048 + i * 32 + k] * coefIn[128 + i] + coefIn[192 + i];
            // BN'd per-b mean over l of A_AP, element i = lane
            mu_ap = muIn[b * 128 + lane] * (1.0f / 64.0f) * coefIn[lane] + coefIn[64 + lane];
        }
        for (int m = 0; m < 32; ++m) {
            int o = __builtin_amdgcn_readfirstlane(o0 + m);
            const float4* Prow = (const float4*)(P + 512 + o * 8);
            float4 p0 = Prow[0], p1 = Prow[1];
            float pu = p0.x * hml[0] + p0.y * hml[1] + p0.z * hml[2] + p0.w * hml[3]
                     + p1.x * hml[4] + p1.y * hml[5] + p1.z * hml[6] + p1.w * hml[7];
            float acc = 0.1f * pu;
            if (!first) {
                const float4* Qrow = (const float4*)(Q + 2 * 4096 + o * 64); // Q1u row
                float t3 = 0.f;
                #pragma unroll
                for (int j = 0; j < 16; ++j) {
                    float4 q = Qrow[j];
                    t3 += q.x * a[4 * j] + q.y * a[4 * j + 1]
                        + q.z * a[4 * j + 2] + q.w * a[4 * j + 3];
                }
                float t4 = reduce64(Q[3 * 4096 + o * 64 + lane] * mu_ap); // Q2u @ mu
                acc += 2.f * t3 + 2.f * t4;
            }
            float v = fmaxf(acc, 0.f);
            if (lane < 32) Aue_out[(size_t)b * 2048 + o * 32 + k] = v;
            float sS = reduce64(v) * 0.5f;       // duplicated halves
            float sQ = reduce64(v * v) * 0.5f;
            if (lane == 0) {
                statsS[(64 + o) * 1024 + b] = sS;
                statsQ[(64 + o) * 1024 + b] = sQ;
                muOut[b * 128 + 64 + o] = sS;
            }
        }
    }
}

// ---------------------------------------------------------------------------
// BN finalize: one block per channel (128 blocks). Reduces 1024 per-block
// partials, computes scale/shift: coef = scAP[64] shAP[64] scUE[64] shUE[64]
// ---------------------------------------------------------------------------
__global__ __launch_bounds__(256) void bn_finalize_kernel(
    const float* __restrict__ statsS, const float* __restrict__ statsQ,
    const float* __restrict__ gamma, const float* __restrict__ beta,
    float* __restrict__ coef) {
    __shared__ float redS[4], redQ[4];
    int ch = blockIdx.x;   // 0..127
    int tid = threadIdx.x;
    float s = 0.f, q = 0.f;
    for (int j = tid; j < 1024; j += 256) {
        s += statsS[ch * 1024 + j];
        q += statsQ[ch * 1024 + j];
    }
    s = reduce64(s);
    q = reduce64(q);
    int wave = tid >> 6, lane = tid & 63;
    if (lane == 0) { redS[wave] = s; redQ[wave] = q; }
    __syncthreads();
    if (tid == 0) {
        s = redS[0] + redS[1] + redS[2] + redS[3];
        q = redQ[0] + redQ[1] + redQ[2] + redQ[3];
        bool ap = ch < 64;
        int o = ap ? ch : ch - 64;
        float cnt = ap ? (float)(B_TOT * L_DIM) : (float)(B_TOT * K_DIM);
        float m = s / cnt;
        float var = q / cnt - m * m;
        float sc = gamma[o] / sqrtf(var + EPS_BN);
        if (ap) { coef[o] = sc;       coef[64 + o] = beta[o] - m * sc; }
        else    { coef[128 + o] = sc; coef[192 + o] = beta[o] - m * sc; }
    }
}

// ---------------------------------------------------------------------------
// Output layer (AP path only, 32 channels, no act/BN). 4 waves x 8 outputs.
// Needs only aAP registers + muUE from stats (linearity trick).
// ---------------------------------------------------------------------------
__global__ __launch_bounds__(256) void layer_out_kernel(
    const float* __restrict__ Aap_in,
    const float* __restrict__ Hmk,
    const float* __restrict__ Qo,  // Q1a | Q2a | Q1u | Q2u, each 32x64
    const float* __restrict__ Po,  // P1a | P1u, each 32x8
    const float* __restrict__ coefIn,
    const float* __restrict__ muIn,
    float* __restrict__ V) {
    int b = blockIdx.x, tid = threadIdx.x;
    int wid = tid >> 6, lane = tid & 63;

    float hmk[8];
    #pragma unroll
    for (int c = 0; c < 8; ++c) hmk[c] = Hmk[(size_t)b * 512 + c * 64 + lane];
    float a[64];
    #pragma unroll
    for (int i = 0; i < 64; ++i)
        a[i] = Aap_in[(size_t)b * 4096 + i * 64 + lane] * coefIn[i] + coefIn[64 + i];
    float mu_ue = muIn[b * 128 + 64 + lane] * (1.0f / 32.0f) * coefIn[128 + lane]
                + coefIn[192 + lane];

    for (int m = 0; m < 8; ++m) {
        int o = __builtin_amdgcn_readfirstlane(wid * 8 + m);
        const float4* Prow = (const float4*)(Po + o * 8);
        float4 p0 = Prow[0], p1 = Prow[1];
        float pa = p0.x * hmk[0] + p0.y * hmk[1] + p0.z * hmk[2] + p0.w * hmk[3]
                 + p1.x * hmk[4] + p1.y * hmk[5] + p1.z * hmk[6] + p1.w * hmk[7];
        const float4* Qrow = (const float4*)(Qo + o * 64);  // Q1 (out) row
        float t1 = 0.f;
        #pragma unroll
        for (int j = 0; j < 16; ++j) {
            float4 q = Qrow[j];
            t1 += q.x * a[4 * j] + q.y * a[4 * j + 1]
                + q.z * a[4 * j + 2] + q.w * a[4 * j + 3];
        }
        float t2 = reduce64(Qo[OUT_K * 64 + o * 64 + lane] * mu_ue); // Q2 @ mu
        V[(size_t)b * 2048 + o * 64 + lane] = 2.f * t1 + 2.f * t2 + 0.1f * pa;
    }
}

// ---------------------------------------------------------------------------
// Final: Phat1[bb,r,l,k] = V[b,k,l]; norm over l; Fhat = Vhat * Phat1/norm*sqrt(L)
// ---------------------------------------------------------------------------
__global__ __launch_bounds__(256) void finalize_kernel(const float* __restrict__ V,
                                                       const float* __restrict__ Vhat,
                                                       float* __restrict__ out) {
    __shared__ float sV[32 * 65];
    __shared__ float inv[32];
    int b = blockIdx.x, tid = threadIdx.x;
    const float4* v4 = (const float4*)(V + (size_t)b * 2048);
    for (int j = tid; j < 512; j += 256) {
        float4 x = v4[j];
        int kk = j >> 4, l0 = (j & 15) * 4;
        float* d = &sV[kk * 65 + l0];
        d[0] = x.x; d[1] = x.y; d[2] = x.z; d[3] = x.w;
    }
    __syncthreads();
    if (tid < 32) {
        float s = 0.f;
        #pragma unroll
        for (int l = 0; l < 64; ++l) { float x = sV[tid * 65 + l]; s += x * x; }
        inv[tid] = 8.0f / sqrtf(s); // sqrt(L)=8
    }
    __syncthreads();
    const float4* vh4 = (const float4*)(Vhat + (size_t)b * 8192);
    float4* o4 = (float4*)out + (size_t)b * 2048;
    for (int j = tid; j < 2048; j += 256) {
        int l = j >> 5, kk = j & 31;
        float p = sV[kk * 65 + l] * inv[kk];
        float4 x = vh4[j];
        x.x *= p; x.y *= p; x.z *= p; x.w *= p;
        o4[j] = x;
    }
}

// ---------------------------------------------------------------------------
extern "C" void kernel_launch(void* const* d_in, const int* in_sizes, int n_in,
                              void* d_out, int out_size, void* d_ws, size_t ws_size,
                              hipStream_t stream) {
    const float* Hr        = (const float*)d_in[0];
    const float* Hi        = (const float*)d_in[1];
    const float* Vhat      = (const float*)d_in[2];
    const float* Qs_hidden = (const float*)d_in[3];
    const float* Ps_hidden = (const float*)d_in[4];
    const float* Qs_out    = (const float*)d_in[5];
    const float* Ps_out    = (const float*)d_in[6];
    const float* bn_gamma  = (const float*)d_in[7];
    const float* bn_beta   = (const float*)d_in[8];
    float* out = (float*)d_out;

    float* ws     = (float*)d_ws;
    float* Hmk    = ws;                    // 1024*512
    float* Hml    = Hmk + 524288;          // 1024*256
    float* AapA   = Hml + 262144;          // 1024*4096
    float* AueA   = AapA + 4194304;        // 1024*2048
    float* AapB   = AueA + 2097152;        // 1024*4096
    float* AueB   = AapB + 4194304;        // 1024*2048
    float* statsS = AueB + 2097152;        // 128*1024
    float* statsQ = statsS + 131072;       // 128*1024
    float* coefA  = statsQ + 131072;       // 256
    float* coefB  = coefA + 256;           // 256
    float* muA    = coefB + 256;           // 1024*128
    float* muB    = muA + 131072;          // 1024*128
    float* V      = AapA;                  // alias: AapA dead after layer 1 reads it

    hipLaunchKernelGGL(hmeans_kernel, dim3(B_TOT), dim3(256), 0, stream, Hr, Hi, Hmk, Hml);

    // hidden layer 0 (inputs are zero -> only P-path)
    hipLaunchKernelGGL(layer_hidden_kernel, dim3(B_TOT), dim3(256), 0, stream,
                       (const float*)nullptr, (const float*)nullptr, AapA, AueA,
                       Hmk, Hml, Qs_hidden, Ps_hidden,
                       (const float*)nullptr, (const float*)nullptr,
                       statsS, statsQ, muA, 1);
    hipLaunchKernelGGL(bn_finalize_kernel, dim3(128), dim3(256), 0, stream,
                       statsS, statsQ, bn_gamma, bn_beta, coefA);

    // hidden layer 1 (applies coefA on load; bias from muA)
    hipLaunchKernelGGL(layer_hidden_kernel, dim3(B_TOT), dim3(256), 0, stream,
                       AapA, AueA, AapB, AueB,
                       Hmk, Hml, Qs_hidden + 4 * 4096, Ps_hidden + 2 * 512,
                       coefA, muA, statsS, statsQ, muB, 0);
    hipLaunchKernelGGL(bn_finalize_kernel, dim3(128), dim3(256), 0, stream,
                       statsS, statsQ, bn_gamma + 64, bn_beta + 64, coefB);

    // output layer (applies coefB on load; bias from muB) + normalization/scale
    hipLaunchKernelGGL(layer_out_kernel, dim3(B_TOT), dim3(256), 0, stream,
                       AapB, Hmk, Qs_out, Ps_out, coefB, muB, V);
    hipLaunchKernelGGL(finalize_kernel, dim3(B_TOT), dim3(256), 0, stream, V, Vhat, out);
}

// Round 5
// 114.602 us; speedup vs baseline: 1.5238x; 1.1219x over previous
//
#include <hip/hip_runtime.h>

#define B_TOT 1024   // BATCH * nbr = 64 * 16
#define L_DIM 64
#define K_DIM 32
#define OUT_K 32
#define EPS_BN 1e-5f

__device__ __forceinline__ float reduce64(float v) {
    #pragma unroll
    for (int w = 1; w < 64; w <<= 1) v += __shfl_xor(v, w);
    return v;
}

// ---------------------------------------------------------------------------
// Kernel 1: Hmk[b,c,l] = mean_k H[b,c,l,k], Hml[b,c,k] = mean_l H[b,c,l,k]
// where H[b, ri*4+u, l, k] = Hhat_{ri}[b, l, k, u]
// LDS row stride padded to 132 words to break column-sum bank conflicts.
// ---------------------------------------------------------------------------
__global__ __launch_bounds__(256, 4) void hmeans_kernel(const float* __restrict__ Hr,
                                                        const float* __restrict__ Hi,
                                                        float* __restrict__ Hmk,
                                                        float* __restrict__ Hml) {
    __shared__ float tile[64 * 132];
    int b = blockIdx.x;
    int tid = threadIdx.x;
    for (int ri = 0; ri < 2; ++ri) {
        const float* src = (ri == 0 ? Hr : Hi) + (size_t)b * 8192;
        const float4* src4 = (const float4*)src;
        for (int j = tid; j < 2048; j += 256) {
            float4 v = src4[j];
            int l = j >> 5, w0 = (j & 31) * 4;
            float* d = &tile[l * 132 + w0];
            d[0] = v.x; d[1] = v.y; d[2] = v.z; d[3] = v.w;
        }
        __syncthreads();
        {
            int l = tid >> 2, u = tid & 3;
            float s = 0.f;
            #pragma unroll
            for (int kk = 0; kk < 32; ++kk) s += tile[l * 132 + kk * 4 + u];
            Hmk[(size_t)b * 512 + (ri * 4 + u) * 64 + l] = s * (1.0f / 32.0f);
        }
        if (tid < 128) {
            int kk = tid >> 2, u = tid & 3;
            float s = 0.f;
            #pragma unroll
            for (int l = 0; l < 64; ++l) s += tile[l * 132 + kk * 4 + u];
            Hml[(size_t)b * 256 + (ri * 4 + u) * 32 + kk] = s * (1.0f / 64.0f);
        }
        __syncthreads();
    }
}

// ---------------------------------------------------------------------------
// Hidden layer, wave-specialized, zero LDS, no in-loop reductions.
// Waves 0,1: AP path (lane = l, aAP[64] in regs). Waves 2,3: UE path
// (lane = k duplicated across halves, aUE[64] in regs).
// Cross-term 2*Q2@mean(BN(A)) comes precomputed per (b,o) via biasIn (s_load).
// BN of previous layer folded into register load (coefIn).
// BN stats (post-ReLU raw sum/sumsq) -> muS/muQ[b*128+ch], via batched
// butterflies (8 chains ILP) once per 8 outputs.
// ---------------------------------------------------------------------------
__global__ __launch_bounds__(256, 4) void layer_hidden_kernel(
    const float* __restrict__ Aap_in, const float* __restrict__ Aue_in,
    float* __restrict__ Aap_out, float* __restrict__ Aue_out,
    const float* __restrict__ Hmk, const float* __restrict__ Hml,
    const float* __restrict__ Q,   // Q1a | Q2a | Q1u | Q2u, each 64x64
    const float* __restrict__ P,   // P1a | P1u, each 64x8
    const float* __restrict__ coefIn, // scAP[64] shAP[64] scUE[64] shUE[64]
    const float* __restrict__ biasIn, // [b][128]: 2*Q2a@muUE_bn | 2*Q2u@muAP_bn
    float* __restrict__ muS, float* __restrict__ muQ,
    int first) {
    int b = blockIdx.x, tid = threadIdx.x;
    int wid = tid >> 6, lane = tid & 63;
    int o0 = __builtin_amdgcn_readfirstlane((wid & 1) * 32);

    if (wid < 2) {
        // ------------------- AP path: lane = l -------------------
        float hmk[8];
        #pragma unroll
        for (int c = 0; c < 8; ++c) hmk[c] = Hmk[(size_t)b * 512 + c * 64 + lane];
        float a[64];
        if (!first) {
            #pragma unroll
            for (int i = 0; i < 64; ++i)
                a[i] = Aap_in[(size_t)b * 4096 + i * 64 + lane] * coefIn[i] + coefIn[64 + i];
        }
        for (int h = 0; h < 4; ++h) {
            float vs[8], qs[8];
            #pragma unroll
            for (int mm = 0; mm < 8; ++mm) {
                int o = o0 + h * 8 + mm;
                float4 p0 = *(const float4*)(P + o * 8);
                float4 p1 = *(const float4*)(P + o * 8 + 4);
                float pa = p0.x * hmk[0] + p0.y * hmk[1] + p0.z * hmk[2] + p0.w * hmk[3]
                         + p1.x * hmk[4] + p1.y * hmk[5] + p1.z * hmk[6] + p1.w * hmk[7];
                float acc = 0.1f * pa;
                if (!first) {
                    acc += biasIn[b * 128 + o];
                    const float4* Qrow = (const float4*)(Q + o * 64);
                    float t1a = 0.f, t1b = 0.f, t1c = 0.f, t1d = 0.f;
                    #pragma unroll
                    for (int j = 0; j < 16; ++j) {
                        float4 q = Qrow[j];
                        t1a += q.x * a[4 * j];
                        t1b += q.y * a[4 * j + 1];
                        t1c += q.z * a[4 * j + 2];
                        t1d += q.w * a[4 * j + 3];
                    }
                    acc += 2.f * ((t1a + t1b) + (t1c + t1d));
                }
                float v = fmaxf(acc, 0.f);
                Aap_out[(size_t)b * 4096 + o * 64 + lane] = v;
                vs[mm] = v; qs[mm] = v * v;
            }
            #pragma unroll
            for (int s = 1; s < 64; s <<= 1) {
                #pragma unroll
                for (int mm = 0; mm < 8; ++mm) {
                    vs[mm] += __shfl_xor(vs[mm], s);
                    qs[mm] += __shfl_xor(qs[mm], s);
                }
            }
            if (lane == 0) {
                #pragma unroll
                for (int mm = 0; mm < 8; ++mm) {
                    muS[b * 128 + o0 + h * 8 + mm] = vs[mm];
                    muQ[b * 128 + o0 + h * 8 + mm] = qs[mm];
                }
            }
        }
    } else {
        // ------------------- UE path: lane = k (duplicated halves) ----------
        int k = lane & 31;
        float hml[8];
        #pragma unroll
        for (int c = 0; c < 8; ++c) hml[c] = Hml[(size_t)b * 256 + c * 32 + k];
        float a[64];
        if (!first) {
            #pragma unroll
            for (int i = 0; i < 64; ++i)
                a[i] = Aue_in[(size_t)b * 2048 + i * 32 + k] * coefIn[128 + i] + coefIn[192 + i];
        }
        for (int h = 0; h < 4; ++h) {
            float vs[8], qs[8];
            #pragma unroll
            for (int mm = 0; mm < 8; ++mm) {
                int o = o0 + h * 8 + mm;
                float4 p0 = *(const float4*)(P + 512 + o * 8);
                float4 p1 = *(const float4*)(P + 512 + o * 8 + 4);
                float pu = p0.x * hml[0] + p0.y * hml[1] + p0.z * hml[2] + p0.w * hml[3]
                         + p1.x * hml[4] + p1.y * hml[5] + p1.z * hml[6] + p1.w * hml[7];
                float acc = 0.1f * pu;
                if (!first) {
                    acc += biasIn[b * 128 + 64 + o];
                    const float4* Qrow = (const float4*)(Q + 2 * 4096 + o * 64);
                    float t1a = 0.f, t1b = 0.f, t1c = 0.f, t1d = 0.f;
                    #pragma unroll
                    for (int j = 0; j < 16; ++j) {
                        float4 q = Qrow[j];
                        t1a += q.x * a[4 * j];
                        t1b += q.y * a[4 * j + 1];
                        t1c += q.z * a[4 * j + 2];
                        t1d += q.w * a[4 * j + 3];
                    }
                    acc += 2.f * ((t1a + t1b) + (t1c + t1d));
                }
                float v = fmaxf(acc, 0.f);
                if (Aue_out && lane < 32) Aue_out[(size_t)b * 2048 + o * 32 + k] = v;
                vs[mm] = v; qs[mm] = v * v;
            }
            #pragma unroll
            for (int s = 1; s < 64; s <<= 1) {
                #pragma unroll
                for (int mm = 0; mm < 8; ++mm) {
                    vs[mm] += __shfl_xor(vs[mm], s);
                    qs[mm] += __shfl_xor(qs[mm], s);
                }
            }
            if (lane == 0) {
                #pragma unroll
                for (int mm = 0; mm < 8; ++mm) {
                    muS[b * 128 + 64 + o0 + h * 8 + mm] = vs[mm] * 0.5f;
                    muQ[b * 128 + 64 + o0 + h * 8 + mm] = qs[mm] * 0.5f;
                }
            }
        }
    }
}

// ---------------------------------------------------------------------------
// BN finalize: block per channel (128). Reduces per-b raw sums (b-major),
// computes scale/shift: coef = scAP[64] shAP[64] scUE[64] shUE[64]
// ---------------------------------------------------------------------------
__global__ __launch_bounds__(256, 8) void bn_finalize_kernel(
    const float* __restrict__ muS, const float* __restrict__ muQ,
    const float* __restrict__ gamma, const float* __restrict__ beta,
    float* __restrict__ coef) {
    __shared__ float redS[4], redQ[4];
    int ch = blockIdx.x;   // 0..127
    int tid = threadIdx.x;
    float s = 0.f, q = 0.f;
    for (int j = tid; j < 1024; j += 256) {
        s += muS[j * 128 + ch];
        q += muQ[j * 128 + ch];
    }
    s = reduce64(s);
    q = reduce64(q);
    int wave = tid >> 6, lane = tid & 63;
    if (lane == 0) { redS[wave] = s; redQ[wave] = q; }
    __syncthreads();
    if (tid == 0) {
        s = redS[0] + redS[1] + redS[2] + redS[3];
        q = redQ[0] + redQ[1] + redQ[2] + redQ[3];
        bool ap = ch < 64;
        int o = ap ? ch : ch - 64;
        float cnt = ap ? (float)(B_TOT * L_DIM) : (float)(B_TOT * K_DIM);
        float m = s / cnt;
        float var = q / cnt - m * m;
        float sc = gamma[o] / sqrtf(var + EPS_BN);
        if (ap) { coef[o] = sc;       coef[64 + o] = beta[o] - m * sc; }
        else    { coef[128 + o] = sc; coef[192 + o] = beta[o] - m * sc; }
    }
}

// ---------------------------------------------------------------------------
// Hidden-layer bias precompute: bias[b][o]      = 2*Q2a[o,:]@muUE_bn[b,:]
//                               bias[b][64+o]   = 2*Q2u[o,:]@muAP_bn[b,:]
// where mu*_bn = BN-affine of the per-b spatial mean (linearity of BN).
// Q is the CONSUMING layer's Q base. Block per b, 128 threads.
// ---------------------------------------------------------------------------
__global__ __launch_bounds__(128, 8) void bias_hidden_kernel(
    const float* __restrict__ Q, const float* __restrict__ coef,
    const float* __restrict__ muS, float* __restrict__ bias) {
    __shared__ float mubn[128];
    int b = blockIdx.x, t = threadIdx.x;
    float raw = muS[b * 128 + t];
    if (t < 64) mubn[t] = raw * (1.0f / 64.0f) * coef[t] + coef[64 + t];
    else        mubn[t] = raw * (1.0f / 32.0f) * coef[64 + t] + coef[128 + t];
    __syncthreads();
    const float* Qm = (t < 64) ? (Q + 4096) : (Q + 3 * 4096);
    const float* mu = (t < 64) ? (mubn + 64) : mubn;
    int o = t & 63;
    const float4* Qrow = (const float4*)(Qm + o * 64);
    float sa = 0.f, sb = 0.f, sc2 = 0.f, sd = 0.f;
    #pragma unroll
    for (int j = 0; j < 16; ++j) {
        float4 q = Qrow[j];
        sa += q.x * mu[4 * j];
        sb += q.y * mu[4 * j + 1];
        sc2 += q.z * mu[4 * j + 2];
        sd += q.w * mu[4 * j + 3];
    }
    bias[b * 128 + t] = 2.f * ((sa + sb) + (sc2 + sd));
}

// ---------------------------------------------------------------------------
// Output-layer bias: biasO[b][o] = 2*Q2o[o,:]@muUE_bn[b,:], o<32.
// ---------------------------------------------------------------------------
__global__ __launch_bounds__(64, 8) void bias_out_kernel(
    const float* __restrict__ Qo, const float* __restrict__ coef,
    const float* __restrict__ muS, float* __restrict__ biasO) {
    __shared__ float mubn[64];
    int b = blockIdx.x, t = threadIdx.x;
    mubn[t] = muS[b * 128 + 64 + t] * (1.0f / 32.0f) * coef[128 + t] + coef[192 + t];
    __syncthreads();
    if (t < 32) {
        const float4* Qrow = (const float4*)(Qo + OUT_K * 64 + t * 64);
        float sa = 0.f, sb = 0.f, sc2 = 0.f, sd = 0.f;
        #pragma unroll
        for (int j = 0; j < 16; ++j) {
            float4 q = Qrow[j];
            sa += q.x * mubn[4 * j];
            sb += q.y * mubn[4 * j + 1];
            sc2 += q.z * mubn[4 * j + 2];
            sd += q.w * mubn[4 * j + 3];
        }
        biasO[b * 32 + t] = 2.f * ((sa + sb) + (sc2 + sd));
    }
}

// ---------------------------------------------------------------------------
// Output layer fused with normalization/scale.
// V[o][l] = 2*Q1o[o,:]@aAP_bn + biasO[b,o] + 0.1*P1o[o,:]@Hmk  -> LDS
// then inv[k] = sqrt(L)/||V[k,:]||, Fhat = Vhat * V[k][l]*inv[k].
// ---------------------------------------------------------------------------
__global__ __launch_bounds__(256, 4) void layer_out_fin_kernel(
    const float* __restrict__ Aap_in,
    const float* __restrict__ Hmk,
    const float* __restrict__ Qo,  // Q1a | Q2a | Q1u | Q2u, each 32x64
    const float* __restrict__ Po,  // P1a | P1u, each 32x8
    const float* __restrict__ coefIn,
    const float* __restrict__ biasO,
    const float* __restrict__ Vhat,
    float* __restrict__ out) {
    __shared__ float sV[32 * 65];
    __shared__ float inv[32];
    int b = blockIdx.x, tid = threadIdx.x;
    int wid = tid >> 6, lane = tid & 63;
    int ob = __builtin_amdgcn_readfirstlane(wid * 8);

    float hmk[8];
    #pragma unroll
    for (int c = 0; c < 8; ++c) hmk[c] = Hmk[(size_t)b * 512 + c * 64 + lane];
    float a[64];
    #pragma unroll
    for (int i = 0; i < 64; ++i)
        a[i] = Aap_in[(size_t)b * 4096 + i * 64 + lane] * coefIn[i] + coefIn[64 + i];

    #pragma unroll
    for (int m = 0; m < 8; ++m) {
        int o = ob + m;
        float4 p0 = *(const float4*)(Po + o * 8);
        float4 p1 = *(const float4*)(Po + o * 8 + 4);
        float pa = p0.x * hmk[0] + p0.y * hmk[1] + p0.z * hmk[2] + p0.w * hmk[3]
                 + p1.x * hmk[4] + p1.y * hmk[5] + p1.z * hmk[6] + p1.w * hmk[7];
        const float4* Qrow = (const float4*)(Qo + o * 64);
        float t1a = 0.f, t1b = 0.f, t1c = 0.f, t1d = 0.f;
        #pragma unroll
        for (int j = 0; j < 16; ++j) {
            float4 q = Qrow[j];
            t1a += q.x * a[4 * j];
            t1b += q.y * a[4 * j + 1];
            t1c += q.z * a[4 * j + 2];
            t1d += q.w * a[4 * j + 3];
        }
        sV[o * 65 + lane] = 2.f * ((t1a + t1b) + (t1c + t1d)) + biasO[b * 32 + o] + 0.1f * pa;
    }
    __syncthreads();
    if (tid < 32) {
        float s = 0.f;
        #pragma unroll
        for (int l = 0; l < 64; ++l) { float x = sV[tid * 65 + l]; s += x * x; }
        inv[tid] = 8.0f / sqrtf(s); // sqrt(L)=8
    }
    __syncthreads();
    const float4* vh4 = (const float4*)(Vhat + (size_t)b * 8192);
    float4* o4 = (float4*)out + (size_t)b * 2048;
    for (int j = tid; j < 2048; j += 256) {
        int l = j >> 5, kk = j & 31;
        float p = sV[kk * 65 + l] * inv[kk];
        float4 x = vh4[j];
        x.x *= p; x.y *= p; x.z *= p; x.w *= p;
        o4[j] = x;
    }
}

// ---------------------------------------------------------------------------
extern "C" void kernel_launch(void* const* d_in, const int* in_sizes, int n_in,
                              void* d_out, int out_size, void* d_ws, size_t ws_size,
                              hipStream_t stream) {
    const float* Hr        = (const float*)d_in[0];
    const float* Hi        = (const float*)d_in[1];
    const float* Vhat      = (const float*)d_in[2];
    const float* Qs_hidden = (const float*)d_in[3];
    const float* Ps_hidden = (const float*)d_in[4];
    const float* Qs_out    = (const float*)d_in[5];
    const float* Ps_out    = (const float*)d_in[6];
    const float* bn_gamma  = (const float*)d_in[7];
    const float* bn_beta   = (const float*)d_in[8];
    float* out = (float*)d_out;

    float* ws    = (float*)d_ws;
    float* Hmk   = ws;                    // 1024*512
    float* Hml   = Hmk + 524288;          // 1024*256
    float* AapA  = Hml + 262144;          // 1024*4096
    float* AueA  = AapA + 4194304;        // 1024*2048
    float* AapB  = AueA + 2097152;        // 1024*4096
    float* muS   = AapB + 4194304;        // 1024*128
    float* muQ   = muS + 131072;          // 1024*128
    float* coefA = muQ + 131072;          // 256
    float* coefB = coefA + 256;           // 256
    float* biasA = coefB + 256;           // 1024*128
    float* biasO = biasA + 131072;        // 1024*32

    hipLaunchKernelGGL(hmeans_kernel, dim3(B_TOT), dim3(256), 0, stream, Hr, Hi, Hmk, Hml);

    // hidden layer 0 (inputs are zero -> only P-path) + stats
    hipLaunchKernelGGL(layer_hidden_kernel, dim3(B_TOT), dim3(256), 0, stream,
                       (const float*)nullptr, (const float*)nullptr, AapA, AueA,
                       Hmk, Hml, Qs_hidden, Ps_hidden,
                       (const float*)nullptr, (const float*)nullptr,
                       muS, muQ, 1);
    hipLaunchKernelGGL(bn_finalize_kernel, dim3(128), dim3(256), 0, stream,
                       muS, muQ, bn_gamma, bn_beta, coefA);
    // bias for layer 1 uses layer 1's Q2 matrices + coefA + layer0 means
    hipLaunchKernelGGL(bias_hidden_kernel, dim3(B_TOT), dim3(128), 0, stream,
                       Qs_hidden + 4 * 4096, coefA, muS, biasA);

    // hidden layer 1 (BN fold coefA, bias biasA) + stats; AueB never consumed
    hipLaunchKernelGGL(layer_hidden_kernel, dim3(B_TOT), dim3(256), 0, stream,
                       AapA, AueA, AapB, (float*)nullptr,
                       Hmk, Hml, Qs_hidden + 4 * 4096, Ps_hidden + 2 * 512,
                       coefA, biasA, muS, muQ, 0);
    hipLaunchKernelGGL(bn_finalize_kernel, dim3(128), dim3(256), 0, stream,
                       muS, muQ, bn_gamma + 64, bn_beta + 64, coefB);
    hipLaunchKernelGGL(bias_out_kernel, dim3(B_TOT), dim3(64), 0, stream,
                       Qs_out, coefB, muS, biasO);

    // output layer fused with normalization/scale
    hipLaunchKernelGGL(layer_out_fin_kernel, dim3(B_TOT), dim3(256), 0, stream,
                       AapB, Hmk, Qs_out, Ps_out, coefB, biasO, Vhat, out);
}

// Round 6
// 110.214 us; speedup vs baseline: 1.5844x; 1.0398x over previous
//
#include <hip/hip_runtime.h>

#define B_TOT 1024   // BATCH * nbr = 64 * 16
#define L_DIM 64
#define K_DIM 32
#define OUT_K 32
#define EPS_BN 1e-5f

__device__ __forceinline__ float reduce64(float v) {
    #pragma unroll
    for (int w = 1; w < 64; w <<= 1) v += __shfl_xor(v, w);
    return v;
}

// ---------------------------------------------------------------------------
// Kernel 1: Hmk[b,c,l] = mean_k H[b,c,l,k], Hml[b,c,k] = mean_l H[b,c,l,k]
// where H[b, ri*4+u, l, k] = Hhat_{ri}[b, l, k, u]
// LDS row stride padded to 132 words to break column-sum bank conflicts.
// ---------------------------------------------------------------------------
__global__ __launch_bounds__(256, 4) void hmeans_kernel(const float* __restrict__ Hr,
                                                        const float* __restrict__ Hi,
                                                        float* __restrict__ Hmk,
                                                        float* __restrict__ Hml) {
    __shared__ float tile[64 * 132];
    int b = blockIdx.x;
    int tid = threadIdx.x;
    for (int ri = 0; ri < 2; ++ri) {
        const float* src = (ri == 0 ? Hr : Hi) + (size_t)b * 8192;
        const float4* src4 = (const float4*)src;
        for (int j = tid; j < 2048; j += 256) {
            float4 v = src4[j];
            int l = j >> 5, w0 = (j & 31) * 4;
            float* d = &tile[l * 132 + w0];
            d[0] = v.x; d[1] = v.y; d[2] = v.z; d[3] = v.w;
        }
        __syncthreads();
        {
            int l = tid >> 2, u = tid & 3;
            float s = 0.f;
            #pragma unroll
            for (int kk = 0; kk < 32; ++kk) s += tile[l * 132 + kk * 4 + u];
            Hmk[(size_t)b * 512 + (ri * 4 + u) * 64 + l] = s * (1.0f / 32.0f);
        }
        if (tid < 128) {
            int kk = tid >> 2, u = tid & 3;
            float s = 0.f;
            #pragma unroll
            for (int l = 0; l < 64; ++l) s += tile[l * 132 + kk * 4 + u];
            Hml[(size_t)b * 256 + (ri * 4 + u) * 32 + kk] = s * (1.0f / 64.0f);
        }
        __syncthreads();
    }
}

// ---------------------------------------------------------------------------
// Hidden layer. Grid 2048: blocks [0,1024) = AP path for b=blockIdx,
// blocks [1024,2048) = UE path for b=blockIdx-1024. The path split is on
// blockIdx (scalar) so control flow stays uniform -> Q/P/bias loads with
// readfirstlane-derived addresses lower to s_load (SMEM), and a[64] stays
// in VGPRs (launch_bounds(256,2) -> 256-VGPR cap).
// Each block: 4 waves x 16 outputs. Lane = l (AP) or k=lane&31 dup (UE).
// Cross-term 2*Q2@mean(BN(A)) precomputed per (b,o) in biasIn.
// BN of previous layer folded into register load (coefIn).
// BN stats (post-ReLU raw sum/sumsq) -> muS/muQ[b*128+ch], batched
// butterflies (8 chains ILP) per 8 outputs.
// ---------------------------------------------------------------------------
__global__ __launch_bounds__(256, 2) void layer_hidden_kernel(
    const float* __restrict__ Aap_in, const float* __restrict__ Aue_in,
    float* __restrict__ Aap_out, float* __restrict__ Aue_out,
    const float* __restrict__ Hmk, const float* __restrict__ Hml,
    const float* __restrict__ Q,   // Q1a | Q2a | Q1u | Q2u, each 64x64
    const float* __restrict__ P,   // P1a | P1u, each 64x8
    const float* __restrict__ coefIn, // scAP[64] shAP[64] scUE[64] shUE[64]
    const float* __restrict__ biasIn, // [b][128]: 2*Q2a@muUE_bn | 2*Q2u@muAP_bn
    float* __restrict__ muS, float* __restrict__ muQ,
    int first) {
    int bb = blockIdx.x, tid = threadIdx.x;
    int wid = tid >> 6, lane = tid & 63;
    int o0 = __builtin_amdgcn_readfirstlane(wid << 4);

    if (bb < B_TOT) {
        // ------------------- AP path: lane = l -------------------
        int b = bb;
        float hmk[8];
        #pragma unroll
        for (int c = 0; c < 8; ++c) hmk[c] = Hmk[(size_t)b * 512 + c * 64 + lane];
        float a[64];
        if (!first) {
            #pragma unroll
            for (int i = 0; i < 64; ++i)
                a[i] = Aap_in[(size_t)b * 4096 + i * 64 + lane] * coefIn[i] + coefIn[64 + i];
        }
        for (int h = 0; h < 2; ++h) {
            float vs[8], qs[8];
            #pragma unroll
            for (int mm = 0; mm < 8; ++mm) {
                int o = o0 + h * 8 + mm;
                float4 p0 = *(const float4*)(P + o * 8);
                float4 p1 = *(const float4*)(P + o * 8 + 4);
                float pa = p0.x * hmk[0] + p0.y * hmk[1] + p0.z * hmk[2] + p0.w * hmk[3]
                         + p1.x * hmk[4] + p1.y * hmk[5] + p1.z * hmk[6] + p1.w * hmk[7];
                float acc = 0.1f * pa;
                if (!first) {
                    acc += biasIn[b * 128 + o];
                    const float4* Qrow = (const float4*)(Q + o * 64);
                    float t1a = 0.f, t1b = 0.f, t1c = 0.f, t1d = 0.f;
                    #pragma unroll
                    for (int j = 0; j < 16; ++j) {
                        float4 q = Qrow[j];
                        t1a += q.x * a[4 * j];
                        t1b += q.y * a[4 * j + 1];
                        t1c += q.z * a[4 * j + 2];
                        t1d += q.w * a[4 * j + 3];
                    }
                    acc += 2.f * ((t1a + t1b) + (t1c + t1d));
                }
                float v = fmaxf(acc, 0.f);
                Aap_out[(size_t)b * 4096 + o * 64 + lane] = v;
                vs[mm] = v; qs[mm] = v * v;
            }
            #pragma unroll
            for (int s = 1; s < 64; s <<= 1) {
                #pragma unroll
                for (int mm = 0; mm < 8; ++mm) {
                    vs[mm] += __shfl_xor(vs[mm], s);
                    qs[mm] += __shfl_xor(qs[mm], s);
                }
            }
            if (lane == 0) {
                #pragma unroll
                for (int mm = 0; mm < 8; ++mm) {
                    muS[b * 128 + o0 + h * 8 + mm] = vs[mm];
                    muQ[b * 128 + o0 + h * 8 + mm] = qs[mm];
                }
            }
        }
    } else {
        // ------------------- UE path: lane = k (duplicated halves) ----------
        int b = bb - B_TOT;
        int k = lane & 31;
        float hml[8];
        #pragma unroll
        for (int c = 0; c < 8; ++c) hml[c] = Hml[(size_t)b * 256 + c * 32 + k];
        float a[64];
        if (!first) {
            #pragma unroll
            for (int i = 0; i < 64; ++i)
                a[i] = Aue_in[(size_t)b * 2048 + i * 32 + k] * coefIn[128 + i] + coefIn[192 + i];
        }
        for (int h = 0; h < 2; ++h) {
            float vs[8], qs[8];
            #pragma unroll
            for (int mm = 0; mm < 8; ++mm) {
                int o = o0 + h * 8 + mm;
                float4 p0 = *(const float4*)(P + 512 + o * 8);
                float4 p1 = *(const float4*)(P + 512 + o * 8 + 4);
                float pu = p0.x * hml[0] + p0.y * hml[1] + p0.z * hml[2] + p0.w * hml[3]
                         + p1.x * hml[4] + p1.y * hml[5] + p1.z * hml[6] + p1.w * hml[7];
                float acc = 0.1f * pu;
                if (!first) {
                    acc += biasIn[b * 128 + 64 + o];
                    const float4* Qrow = (const float4*)(Q + 2 * 4096 + o * 64);
                    float t1a = 0.f, t1b = 0.f, t1c = 0.f, t1d = 0.f;
                    #pragma unroll
                    for (int j = 0; j < 16; ++j) {
                        float4 q = Qrow[j];
                        t1a += q.x * a[4 * j];
                        t1b += q.y * a[4 * j + 1];
                        t1c += q.z * a[4 * j + 2];
                        t1d += q.w * a[4 * j + 3];
                    }
                    acc += 2.f * ((t1a + t1b) + (t1c + t1d));
                }
                float v = fmaxf(acc, 0.f);
                if (Aue_out != nullptr && lane < 32)
                    Aue_out[(size_t)b * 2048 + o * 32 + k] = v;
                vs[mm] = v; qs[mm] = v * v;
            }
            #pragma unroll
            for (int s = 1; s < 64; s <<= 1) {
                #pragma unroll
                for (int mm = 0; mm < 8; ++mm) {
                    vs[mm] += __shfl_xor(vs[mm], s);
                    qs[mm] += __shfl_xor(qs[mm], s);
                }
            }
            if (lane == 0) {
                #pragma unroll
                for (int mm = 0; mm < 8; ++mm) {
                    muS[b * 128 + 64 + o0 + h * 8 + mm] = vs[mm] * 0.5f;
                    muQ[b * 128 + 64 + o0 + h * 8 + mm] = qs[mm] * 0.5f;
                }
            }
        }
    }
}

// ---------------------------------------------------------------------------
// BN finalize: block per channel (128). Reduces per-b raw sums (b-major),
// computes scale/shift: coef = scAP[64] shAP[64] scUE[64] shUE[64]
// ---------------------------------------------------------------------------
__global__ __launch_bounds__(256, 8) void bn_finalize_kernel(
    const float* __restrict__ muS, const float* __restrict__ muQ,
    const float* __restrict__ gamma, const float* __restrict__ beta,
    float* __restrict__ coef) {
    __shared__ float redS[4], redQ[4];
    int ch = blockIdx.x;   // 0..127
    int tid = threadIdx.x;
    float s = 0.f, q = 0.f;
    for (int j = tid; j < 1024; j += 256) {
        s += muS[j * 128 + ch];
        q += muQ[j * 128 + ch];
    }
    s = reduce64(s);
    q = reduce64(q);
    int wave = tid >> 6, lane = tid & 63;
    if (lane == 0) { redS[wave] = s; redQ[wave] = q; }
    __syncthreads();
    if (tid == 0) {
        s = redS[0] + redS[1] + redS[2] + redS[3];
        q = redQ[0] + redQ[1] + redQ[2] + redQ[3];
        bool ap = ch < 64;
        int o = ap ? ch : ch - 64;
        float cnt = ap ? (float)(B_TOT * L_DIM) : (float)(B_TOT * K_DIM);
        float m = s / cnt;
        float var = q / cnt - m * m;
        float sc = gamma[o] / sqrtf(var + EPS_BN);
        if (ap) { coef[o] = sc;       coef[64 + o] = beta[o] - m * sc; }
        else    { coef[128 + o] = sc; coef[192 + o] = beta[o] - m * sc; }
    }
}

// ---------------------------------------------------------------------------
// Hidden-layer bias precompute: bias[b][o]      = 2*Q2a[o,:]@muUE_bn[b,:]
//                               bias[b][64+o]   = 2*Q2u[o,:]@muAP_bn[b,:]
// where mu*_bn = BN-affine of the per-b spatial mean (linearity of BN).
// Q is the CONSUMING layer's Q base. Block per b, 128 threads.
// ---------------------------------------------------------------------------
__global__ __launch_bounds__(128, 8) void bias_hidden_kernel(
    const float* __restrict__ Q, const float* __restrict__ coef,
    const float* __restrict__ muS, float* __restrict__ bias) {
    __shared__ float mubn[128];
    int b = blockIdx.x, t = threadIdx.x;
    float raw = muS[b * 128 + t];
    if (t < 64) mubn[t] = raw * (1.0f / 64.0f) * coef[t] + coef[64 + t];
    else        mubn[t] = raw * (1.0f / 32.0f) * coef[64 + t] + coef[128 + t];
    __syncthreads();
    const float* Qm = (t < 64) ? (Q + 4096) : (Q + 3 * 4096);
    const float* mu = (t < 64) ? (mubn + 64) : mubn;
    int o = t & 63;
    const float4* Qrow = (const float4*)(Qm + o * 64);
    float sa = 0.f, sb = 0.f, sc2 = 0.f, sd = 0.f;
    #pragma unroll
    for (int j = 0; j < 16; ++j) {
        float4 q = Qrow[j];
        sa += q.x * mu[4 * j];
        sb += q.y * mu[4 * j + 1];
        sc2 += q.z * mu[4 * j + 2];
        sd += q.w * mu[4 * j + 3];
    }
    bias[b * 128 + t] = 2.f * ((sa + sb) + (sc2 + sd));
}

// ---------------------------------------------------------------------------
// Output-layer bias: biasO[b][o] = 2*Q2o[o,:]@muUE_bn[b,:], o<32.
// ---------------------------------------------------------------------------
__global__ __launch_bounds__(64, 8) void bias_out_kernel(
    const float* __restrict__ Qo, const float* __restrict__ coef,
    const float* __restrict__ muS, float* __restrict__ biasO) {
    __shared__ float mubn[64];
    int b = blockIdx.x, t = threadIdx.x;
    mubn[t] = muS[b * 128 + 64 + t] * (1.0f / 32.0f) * coef[128 + t] + coef[192 + t];
    __syncthreads();
    if (t < 32) {
        const float4* Qrow = (const float4*)(Qo + OUT_K * 64 + t * 64);
        float sa = 0.f, sb = 0.f, sc2 = 0.f, sd = 0.f;
        #pragma unroll
        for (int j = 0; j < 16; ++j) {
            float4 q = Qrow[j];
            sa += q.x * mubn[4 * j];
            sb += q.y * mubn[4 * j + 1];
            sc2 += q.z * mubn[4 * j + 2];
            sd += q.w * mubn[4 * j + 3];
        }
        biasO[b * 32 + t] = 2.f * ((sa + sb) + (sc2 + sd));
    }
}

// ---------------------------------------------------------------------------
// Output layer fused with normalization/scale.
// V[o][l] = 2*Q1o[o,:]@aAP_bn + biasO[b,o] + 0.1*P1o[o,:]@Hmk  -> LDS
// then inv[k] = sqrt(L)/||V[k,:]||, Fhat = Vhat * V[k][l]*inv[k].
// Uniform CF -> Q/P loads scalarize; (256,2) keeps a[64] in VGPRs.
// ---------------------------------------------------------------------------
__global__ __launch_bounds__(256, 2) void layer_out_fin_kernel(
    const float* __restrict__ Aap_in,
    const float* __restrict__ Hmk,
    const float* __restrict__ Qo,  // Q1a | Q2a | Q1u | Q2u, each 32x64
    const float* __restrict__ Po,  // P1a | P1u, each 32x8
    const float* __restrict__ coefIn,
    const float* __restrict__ biasO,
    const float* __restrict__ Vhat,
    float* __restrict__ out) {
    __shared__ float sV[32 * 65];
    __shared__ float inv[32];
    int b = blockIdx.x, tid = threadIdx.x;
    int wid = tid >> 6, lane = tid & 63;
    int ob = __builtin_amdgcn_readfirstlane(wid << 3);

    float hmk[8];
    #pragma unroll
    for (int c = 0; c < 8; ++c) hmk[c] = Hmk[(size_t)b * 512 + c * 64 + lane];
    float a[64];
    #pragma unroll
    for (int i = 0; i < 64; ++i)
        a[i] = Aap_in[(size_t)b * 4096 + i * 64 + lane] * coefIn[i] + coefIn[64 + i];

    #pragma unroll
    for (int m = 0; m < 8; ++m) {
        int o = ob + m;
        float4 p0 = *(const float4*)(Po + o * 8);
        float4 p1 = *(const float4*)(Po + o * 8 + 4);
        float pa = p0.x * hmk[0] + p0.y * hmk[1] + p0.z * hmk[2] + p0.w * hmk[3]
                 + p1.x * hmk[4] + p1.y * hmk[5] + p1.z * hmk[6] + p1.w * hmk[7];
        const float4* Qrow = (const float4*)(Qo + o * 64);
        float t1a = 0.f, t1b = 0.f, t1c = 0.f, t1d = 0.f;
        #pragma unroll
        for (int j = 0; j < 16; ++j) {
            float4 q = Qrow[j];
            t1a += q.x * a[4 * j];
            t1b += q.y * a[4 * j + 1];
            t1c += q.z * a[4 * j + 2];
            t1d += q.w * a[4 * j + 3];
        }
        sV[o * 65 + lane] = 2.f * ((t1a + t1b) + (t1c + t1d)) + biasO[b * 32 + o] + 0.1f * pa;
    }
    __syncthreads();
    if (tid < 32) {
        float s = 0.f;
        #pragma unroll
        for (int l = 0; l < 64; ++l) { float x = sV[tid * 65 + l]; s += x * x; }
        inv[tid] = 8.0f / sqrtf(s); // sqrt(L)=8
    }
    __syncthreads();
    const float4* vh4 = (const float4*)(Vhat + (size_t)b * 8192);
    float4* o4 = (float4*)out + (size_t)b * 2048;
    for (int j = tid; j < 2048; j += 256) {
        int l = j >> 5, kk = j & 31;
        float p = sV[kk * 65 + l] * inv[kk];
        float4 x = vh4[j];
        x.x *= p; x.y *= p; x.z *= p; x.w *= p;
        o4[j] = x;
    }
}

// ---------------------------------------------------------------------------
extern "C" void kernel_launch(void* const* d_in, const int* in_sizes, int n_in,
                              void* d_out, int out_size, void* d_ws, size_t ws_size,
                              hipStream_t stream) {
    const float* Hr        = (const float*)d_in[0];
    const float* Hi        = (const float*)d_in[1];
    const float* Vhat      = (const float*)d_in[2];
    const float* Qs_hidden = (const float*)d_in[3];
    const float* Ps_hidden = (const float*)d_in[4];
    const float* Qs_out    = (const float*)d_in[5];
    const float* Ps_out    = (const float*)d_in[6];
    const float* bn_gamma  = (const float*)d_in[7];
    const float* bn_beta   = (const float*)d_in[8];
    float* out = (float*)d_out;

    float* ws    = (float*)d_ws;
    float* Hmk   = ws;                    // 1024*512
    float* Hml   = Hmk + 524288;          // 1024*256
    float* AapA  = Hml + 262144;          // 1024*4096
    float* AueA  = AapA + 4194304;        // 1024*2048
    float* AapB  = AueA + 2097152;        // 1024*4096
    float* muS   = AapB + 4194304;        // 1024*128
    float* muQ   = muS + 131072;          // 1024*128
    float* coefA = muQ + 131072;          // 256
    float* coefB = coefA + 256;           // 256
    float* biasA = coefB + 256;           // 1024*128
    float* biasO = biasA + 131072;        // 1024*32

    hipLaunchKernelGGL(hmeans_kernel, dim3(B_TOT), dim3(256), 0, stream, Hr, Hi, Hmk, Hml);

    // hidden layer 0 (inputs are zero -> only P-path) + stats
    hipLaunchKernelGGL(layer_hidden_kernel, dim3(2 * B_TOT), dim3(256), 0, stream,
                       (const float*)nullptr, (const float*)nullptr, AapA, AueA,
                       Hmk, Hml, Qs_hidden, Ps_hidden,
                       (const float*)nullptr, (const float*)nullptr,
                       muS, muQ, 1);
    hipLaunchKernelGGL(bn_finalize_kernel, dim3(128), dim3(256), 0, stream,
                       muS, muQ, bn_gamma, bn_beta, coefA);
    // bias for layer 1 uses layer 1's Q2 matrices + coefA + layer0 means
    hipLaunchKernelGGL(bias_hidden_kernel, dim3(B_TOT), dim3(128), 0, stream,
                       Qs_hidden + 4 * 4096, coefA, muS, biasA);

    // hidden layer 1 (BN fold coefA, bias biasA) + stats; AueB never consumed
    hipLaunchKernelGGL(layer_hidden_kernel, dim3(2 * B_TOT), dim3(256), 0, stream,
                       AapA, AueA, AapB, (float*)nullptr,
                       Hmk, Hml, Qs_hidden + 4 * 4096, Ps_hidden + 2 * 512,
                       coefA, biasA, muS, muQ, 0);
    hipLaunchKernelGGL(bn_finalize_kernel, dim3(128), dim3(256), 0, stream,
                       muS, muQ, bn_gamma + 64, bn_beta + 64, coefB);
    hipLaunchKernelGGL(bias_out_kernel, dim3(B_TOT), dim3(64), 0, stream,
                       Qs_out, coefB, muS, biasO);

    // output layer fused with normalization/scale
    hipLaunchKernelGGL(layer_out_fin_kernel, dim3(B_TOT), dim3(256), 0, stream,
                       AapB, Hmk, Qs_out, Ps_out, coefB, biasO, Vhat, out);
}